// Round 11
// baseline (89.796 us; speedup 1.0000x reference)
//
#include <hip/hip_runtime.h>
#include <hip/hip_bf16.h>

// Problem constants
#define B_    64
#define S_    512
#define H_    1024
#define HH_   (H_*H_)
#define T_    4
#define NF_   12
#define TNF_  48      // T*NF
#define NP_   66      // NF*(NF-1)/2
#define OUTC_ 127     // 1 + 48 + 66 + 12

// score counts
#define NSENT_ (B_*TNF_)   // 3072
#define NSTEP_ (B_*NP_)    // 4224
#define NABD_  (B_*NF_)    // 768
#define NCLS_  (B_)        // 64

// A-buffer rows (bf16, row length 1024)
#define AROW_FCT   0      // 768 rows (b*12+f)
#define AROW_TGT   768    // 256 rows (b*4+t)
#define AROW_TSD   1024   // 64 rows
#define AROW_CLS   1088   // 64 rows
#define AROWS_     1152

// G rows (bf16, row length 1024): fsent, s1, s2, af, tsent, at, cls
#define GROW_FSENT 0
#define GROW_S1    768
#define GROW_S2    1536
#define GROW_AF    2304
#define GROW_TSENT 3072
#define GROW_AT    3328
#define GROW_CLS   3392
#define GROWS_     3456

typedef __bf16 bf16x8 __attribute__((ext_vector_type(8)));
typedef float  f32x4  __attribute__((ext_vector_type(4)));
typedef __attribute__((address_space(1))) const unsigned int gcu32;
typedef __attribute__((address_space(3))) unsigned int lu32;

__device__ __forceinline__ ushort f2bf(float x) {
    union { float f; unsigned u; } c; c.f = x;
    unsigned r = c.u + 0x7fffu + ((c.u >> 16) & 1u);
    return (ushort)(r >> 16);
}
__device__ __forceinline__ float bflo(unsigned u) {
    union { unsigned u; float f; } c; c.u = u << 16; return c.f;
}
__device__ __forceinline__ float bfhi(unsigned u) {
    union { unsigned u; float f; } c; c.u = u & 0xffff0000u; return c.f;
}

// ---------------------------------------------------------------------------
// Prep (merged): [0,1024)    segment means -> bf16 A rows
//                [1024,1088) cls cast
//                [1088,8256) W1 transpose-cast
//                [8256,8320) tside (recomputed from seq; no fp32 staging)
// ---------------------------------------------------------------------------
__global__ __launch_bounds__(256) void prep_kernel(
    const float* __restrict__ seq, const int* __restrict__ toffs,
    const int* __restrict__ foffs, const float* __restrict__ cls,
    const float* __restrict__ sw1, const float* __restrict__ pw1,
    const float* __restrict__ aw1, const float* __restrict__ cw1,
    ushort* __restrict__ Abf, ushort* __restrict__ Wt)
{
    int blk = blockIdx.x;
    int tid = threadIdx.x;

    if (blk < 1024) {
        // ---- segment mean ----
        int b = blk >> 4;
        int k = blk & 15;
        int start, end, arow;
        if (k < T_) {
            start = toffs[(b*T_ + k)*2];
            end   = toffs[(b*T_ + k)*2 + 1];
            arow  = AROW_TGT + b*T_ + k;
        } else {
            int f = k - T_;
            start = foffs[(b*NF_ + f)*2];
            end   = foffs[(b*NF_ + f)*2 + 1];
            arow  = AROW_FCT + b*NF_ + f;
        }
        int h0 = tid * 4;
        const float* base = seq + ((size_t)b * S_ + start) * H_ + h0;
        float4 s = make_float4(0.f, 0.f, 0.f, 0.f);
        int n = end - start;
        #pragma unroll 4
        for (int r = 0; r < n; ++r) {
            float4 v = *(const float4*)(base + (size_t)r * H_);
            s.x += v.x; s.y += v.y; s.z += v.z; s.w += v.w;
        }
        float inv = 1.f / (float)n;
        ushort4 q;
        q.x = f2bf(s.x*inv); q.y = f2bf(s.y*inv);
        q.z = f2bf(s.z*inv); q.w = f2bf(s.w*inv);
        *(ushort4*)(Abf + (size_t)arow * H_ + h0) = q;
    } else if (blk < 1088) {
        // ---- cls cast ----
        int b = blk - 1024;
        int h0 = tid * 4;
        float4 c = *(const float4*)(cls + (size_t)b * H_ + h0);
        ushort4 qc; qc.x = f2bf(c.x); qc.y = f2bf(c.y); qc.z = f2bf(c.z); qc.w = f2bf(c.w);
        *(ushort4*)(Abf + (size_t)(AROW_CLS + b) * H_ + h0) = qc;
    } else if (blk < 8256) {
        // ---- transpose-cast 32x32 tile of one of 7 fp32 [1024][1024] blocks
        // src order: 0 sw1-top, 1 pw1-top, 2 pw1-bot, 3 aw1-bot, 4 sw1-bot,
        //            5 aw1-top, 6 cw1
        __shared__ float Tt[32][33];
        int idx2 = blk - 1088;
        int z = idx2 >> 10;
        int rem = idx2 & 1023;
        int k0 = (rem >> 5) * 32;
        int n0 = (rem & 31) * 32;
        const float* src;
        switch (z) {
            case 0: src = sw1; break;
            case 1: src = pw1; break;
            case 2: src = pw1 + HH_; break;
            case 3: src = aw1 + HH_; break;
            case 4: src = sw1 + HH_; break;
            case 5: src = aw1; break;
            default: src = cw1; break;
        }
        int ty = tid >> 3, tx = tid & 7;
        float4 v = *(const float4*)(src + (size_t)(k0 + ty) * H_ + n0 + tx*4);
        Tt[ty][tx*4 + 0] = v.x; Tt[ty][tx*4 + 1] = v.y;
        Tt[ty][tx*4 + 2] = v.z; Tt[ty][tx*4 + 3] = v.w;
        __syncthreads();
        int nx = ty, kx = tx;
        ushort4 q;
        q.x = f2bf(Tt[kx*4 + 0][nx]); q.y = f2bf(Tt[kx*4 + 1][nx]);
        q.z = f2bf(Tt[kx*4 + 2][nx]); q.w = f2bf(Tt[kx*4 + 3][nx]);
        *(ushort4*)(Wt + (size_t)z * HH_ + (size_t)(n0 + nx) * H_ + k0 + kx*4) = q;
    } else {
        // ---- tside: mean over T of per-segment means, direct from seq ----
        int b = blk - 8256;
        int h0 = tid * 4;
        float4 acc = make_float4(0.f, 0.f, 0.f, 0.f);
        #pragma unroll
        for (int t = 0; t < T_; ++t) {
            int start = toffs[(b*T_ + t)*2];
            int end   = toffs[(b*T_ + t)*2 + 1];
            const float* base = seq + ((size_t)b * S_ + start) * H_ + h0;
            float4 s = make_float4(0.f, 0.f, 0.f, 0.f);
            int n = end - start;
            #pragma unroll 4
            for (int r = 0; r < n; ++r) {
                float4 v = *(const float4*)(base + (size_t)r * H_);
                s.x += v.x; s.y += v.y; s.z += v.z; s.w += v.w;
            }
            float inv = 1.f / (float)n;
            acc.x += s.x*inv; acc.y += s.y*inv;
            acc.z += s.z*inv; acc.w += s.w*inv;
        }
        ushort4 q;
        q.x = f2bf(acc.x*0.25f); q.y = f2bf(acc.y*0.25f);
        q.z = f2bf(acc.z*0.25f); q.w = f2bf(acc.w*0.25f);
        *(ushort4*)(Abf + (size_t)(AROW_TSD + b) * H_ + h0) = q;
    }
}

// ---------------------------------------------------------------------------
// Merged bf16 MFMA GEMM — FROZEN from R10 (m97-regime): 64x64 tile, 2 waves,
// 864 blocks, BK=32, single LDS buffer, plain 2-barrier loop.
// ---------------------------------------------------------------------------
__global__ __launch_bounds__(128) void gemm_bf16_kernel(
    const ushort* __restrict__ Abf, const ushort* __restrict__ Wt,
    ushort* __restrict__ G)
{
    __shared__ __align__(16) ushort As[64*32];   // 4KB
    __shared__ __align__(16) ushort Bs[64*32];   // 4KB

    const int mt = blockIdx.x;       // 0..53 (64-row tiles)
    const int n0 = blockIdx.y * 64;  // 0..960

    int arow, wsel, grow;
    if (mt < 48)      { wsel = mt / 12; int m = mt % 12;
                        arow = AROW_FCT + m*64; grow = wsel*768 + m*64; }
    else if (mt < 52) { wsel = 4; arow = AROW_TGT + (mt-48)*64;
                        grow = GROW_TSENT + (mt-48)*64; }
    else if (mt == 52){ wsel = 5; arow = AROW_TSD; grow = GROW_AT; }
    else              { wsel = 6; arow = AROW_CLS; grow = GROW_CLS; }

    const int tid  = threadIdx.x;
    const int lane = tid & 63;
    const int w    = tid >> 6;       // 0,1

    const int srow = lane >> 2;                              // 0..15
    const int scol = ((lane & 3) ^ ((lane >> 3) & 3)) * 8;   // swizzled chunk
    const ushort* gA0 = Abf + (size_t)(arow + w*32 + srow) * H_ + scol;
    const ushort* gA1 = gA0 + (size_t)16 * H_;
    const ushort* gB0 = Wt + (size_t)wsel * HH_
                        + (size_t)(n0 + w*32 + srow) * H_ + scol;
    const ushort* gB1 = gB0 + (size_t)16 * H_;
    ushort* ldsA = As + w * 1024;
    ushort* ldsB = Bs + w * 1024;

    const int frr  = lane & 15;
    const int c0   = lane >> 4;
    const int swz8 = (c0 ^ ((frr >> 1) & 3)) * 8;
    const int offA = (w*32 + frr) * 32 + swz8;
    const int offB = frr * 32 + swz8;

    f32x4 acc[2][4];
    #pragma unroll
    for (int i = 0; i < 2; ++i)
        #pragma unroll
        for (int j = 0; j < 4; ++j)
            acc[i][j] = (f32x4){0.f, 0.f, 0.f, 0.f};

    #pragma unroll 1
    for (int t = 0; t < 32; ++t) {
        const int kk = t * 32;
        __syncthreads();
        __builtin_amdgcn_global_load_lds((gcu32*)(gA0 + kk), (lu32*)ldsA,         16, 0, 0);
        __builtin_amdgcn_global_load_lds((gcu32*)(gA1 + kk), (lu32*)(ldsA + 512), 16, 0, 0);
        __builtin_amdgcn_global_load_lds((gcu32*)(gB0 + kk), (lu32*)ldsB,         16, 0, 0);
        __builtin_amdgcn_global_load_lds((gcu32*)(gB1 + kk), (lu32*)(ldsB + 512), 16, 0, 0);
        __syncthreads();

        bf16x8 a0 = *(const bf16x8*)(As + offA);
        bf16x8 a1 = *(const bf16x8*)(As + offA + 512);
        bf16x8 b0 = *(const bf16x8*)(Bs + offB);
        bf16x8 b1 = *(const bf16x8*)(Bs + offB + 512);
        bf16x8 b2 = *(const bf16x8*)(Bs + offB + 1024);
        bf16x8 b3 = *(const bf16x8*)(Bs + offB + 1536);

        acc[0][0] = __builtin_amdgcn_mfma_f32_16x16x32_bf16(a0, b0, acc[0][0], 0, 0, 0);
        acc[0][1] = __builtin_amdgcn_mfma_f32_16x16x32_bf16(a0, b1, acc[0][1], 0, 0, 0);
        acc[0][2] = __builtin_amdgcn_mfma_f32_16x16x32_bf16(a0, b2, acc[0][2], 0, 0, 0);
        acc[0][3] = __builtin_amdgcn_mfma_f32_16x16x32_bf16(a0, b3, acc[0][3], 0, 0, 0);
        acc[1][0] = __builtin_amdgcn_mfma_f32_16x16x32_bf16(a1, b0, acc[1][0], 0, 0, 0);
        acc[1][1] = __builtin_amdgcn_mfma_f32_16x16x32_bf16(a1, b1, acc[1][1], 0, 0, 0);
        acc[1][2] = __builtin_amdgcn_mfma_f32_16x16x32_bf16(a1, b2, acc[1][2], 0, 0, 0);
        acc[1][3] = __builtin_amdgcn_mfma_f32_16x16x32_bf16(a1, b3, acc[1][3], 0, 0, 0);
    }

    // C/D layout: col = lane&15, row = (lane>>4)*4 + reg   [verified m89]
    const int r0 = (lane >> 4) * 4;
    const int cc = lane & 15;
    #pragma unroll
    for (int i = 0; i < 2; ++i) {
        #pragma unroll
        for (int r = 0; r < 4; ++r) {
            size_t gr = (size_t)(grow + w*32 + i*16 + r0 + r) * H_ + n0 + cc;
            #pragma unroll
            for (int j = 0; j < 4; ++j)
                G[gr + j*16] = f2bf(acc[i][j][r]);
        }
    }
}

// ---------------------------------------------------------------------------
// Grouped combine: grid (64, 3). Block (b, kind) stages its batch's unique
// G rows into LDS once, then 4 waves compute scores (one wave per score,
// U/V read from LDS). kind 0: sent (16 rows, 48 scores); kind 1: step
// (24 rows, 66 scores); kind 2: abd+cls (14 rows, 13 scores).
// ---------------------------------------------------------------------------
__global__ __launch_bounds__(256) void combine_kernel(
    const ushort* __restrict__ G,
    const float* __restrict__ sb1, const float* __restrict__ sw2,
    const float* __restrict__ pb1, const float* __restrict__ pw2,
    const float* __restrict__ ab1, const float* __restrict__ aw2,
    const float* __restrict__ cb1, const float* __restrict__ cw2,
    float* __restrict__ ssent, float* __restrict__ sstep,
    float* __restrict__ sabd, float* __restrict__ scls)
{
    __shared__ __align__(16) ushort rows[24 * 1024];   // 48 KB max

    const int b    = blockIdx.x;
    const int kind = blockIdx.y;
    const int tid  = threadIdx.x;
    const int wv   = tid >> 6;
    const int lane = tid & 63;

    const int nrows = (kind == 0) ? 16 : (kind == 1) ? 24 : 14;

    // ---- stage rows: each iteration copies one 2KB row (8B/thread) ----
    for (int r = 0; r < nrows; ++r) {
        int gi;
        if (kind == 0)      gi = (r < 12) ? (GROW_FSENT + b*NF_ + r)
                                          : (GROW_TSENT + b*T_ + (r - 12));
        else if (kind == 1) gi = (r < 12) ? (GROW_S1 + b*NF_ + r)
                                          : (GROW_S2 + b*NF_ + (r - 12));
        else                gi = (r < 12) ? (GROW_AF + b*NF_ + r)
                                          : ((r == 12) ? (GROW_AT + b)
                                                       : (GROW_CLS + b));
        *(uint2*)(rows + r*1024 + tid*4) =
            *(const uint2*)(G + (size_t)gi * H_ + tid*4);
    }
    __syncthreads();

    const int nsc = (kind == 0) ? TNF_ : (kind == 1) ? NP_ : 13;
    for (int s = wv; s < nsc; s += 4) {
        const ushort *U, *V;
        const float *b1, *w2;
        float* outp;
        if (kind == 0) {
            int t = s / NF_, f = s % NF_;
            U = rows + f*1024; V = rows + (12 + t)*1024;
            b1 = sb1; w2 = sw2; outp = ssent + b*TNF_ + s;
        } else if (kind == 1) {
            int i = 0, rem = s, cnt = NF_ - 1;
            while (rem >= cnt) { rem -= cnt; --cnt; ++i; }
            int j = i + 1 + rem;
            U = rows + i*1024; V = rows + (12 + j)*1024;
            b1 = pb1; w2 = pw2; outp = sstep + b*NP_ + s;
        } else if (s < 12) {
            U = rows + 12*1024; V = rows + s*1024;
            b1 = ab1; w2 = aw2; outp = sabd + b*NF_ + s;
        } else {
            U = rows + 13*1024; V = nullptr;
            b1 = cb1; w2 = cw2; outp = scls + b;
        }

        float acc = 0.f;
        #pragma unroll
        for (int h = 0; h < 2; ++h) {
            int nb = h * 512 + lane * 8;
            uint4 uu = *(const uint4*)(U + nb);
            float us[8] = { bflo(uu.x), bfhi(uu.x), bflo(uu.y), bfhi(uu.y),
                            bflo(uu.z), bfhi(uu.z), bflo(uu.w), bfhi(uu.w) };
            if (V) {
                uint4 vv = *(const uint4*)(V + nb);
                us[0] += bflo(vv.x); us[1] += bfhi(vv.x);
                us[2] += bflo(vv.y); us[3] += bfhi(vv.y);
                us[4] += bflo(vv.z); us[5] += bfhi(vv.z);
                us[6] += bflo(vv.w); us[7] += bfhi(vv.w);
            }
            float4 bA = *(const float4*)(b1 + nb);
            float4 bB = *(const float4*)(b1 + nb + 4);
            float4 wA = *(const float4*)(w2 + nb);
            float4 wB = *(const float4*)(w2 + nb + 4);
            acc = fmaf(fmaxf(us[0] + bA.x, 0.f), wA.x, acc);
            acc = fmaf(fmaxf(us[1] + bA.y, 0.f), wA.y, acc);
            acc = fmaf(fmaxf(us[2] + bA.z, 0.f), wA.z, acc);
            acc = fmaf(fmaxf(us[3] + bA.w, 0.f), wA.w, acc);
            acc = fmaf(fmaxf(us[4] + bB.x, 0.f), wB.x, acc);
            acc = fmaf(fmaxf(us[5] + bB.y, 0.f), wB.y, acc);
            acc = fmaf(fmaxf(us[6] + bB.z, 0.f), wB.z, acc);
            acc = fmaf(fmaxf(us[7] + bB.w, 0.f), wB.w, acc);
        }
        #pragma unroll
        for (int msk = 1; msk < 64; msk <<= 1)
            acc += __shfl_xor(acc, msk);
        if (lane == 0) *outp = acc;
    }
}

// ---------------------------------------------------------------------------
// Finalize: sigmoids, masked max/mean, lambda blend, 78-way softmax, output
// ---------------------------------------------------------------------------
__global__ __launch_bounds__(128) void finalize_kernel(
    const float* __restrict__ s_sent, const float* __restrict__ s_step,
    const float* __restrict__ s_abd, const float* __restrict__ s_cls,
    const float* __restrict__ mask, const float* __restrict__ lam,
    const float* __restrict__ sent_b2, const float* __restrict__ step_b2,
    const float* __restrict__ state_b2, const float* __restrict__ abd_b2,
    float* __restrict__ out)
{
    int b = blockIdx.x;
    int tid = threadIdx.x;
    __shared__ float fs[TNF_];
    __shared__ float sc[NP_ + NF_];
    __shared__ float mpf[NF_];
    __shared__ float smax, ssum;

    if (tid < TNF_) {
        float v = 1.f / (1.f + expf(-(s_sent[b*TNF_ + tid] + sent_b2[0])));
        fs[tid] = v;
        out[(size_t)b*OUTC_ + 1 + tid] = v;
    }
    if (tid < NP_)
        sc[tid] = s_step[b*NP_ + tid] + step_b2[0];
    else if (tid < NP_ + NF_)
        sc[tid] = s_abd[b*NF_ + (tid - NP_)] + abd_b2[0];
    __syncthreads();

    if (tid < NF_) {
        float m = -1e30f;
        for (int j = 0; j < T_; ++j)
            m = fmaxf(m, fs[tid*T_ + j] * mask[((size_t)b*NF_ + tid)*T_ + j]);
        mpf[tid] = m;
    }
    __syncthreads();

    if (tid == 0) {
        float sf = 0.f;
        for (int i = 0; i < NF_; ++i) sf += mpf[i];
        sf *= (1.f / NF_);
        float scls2 = 1.f / (1.f + expf(-(s_cls[b] + state_b2[0])));
        float l0 = lam[0], l1 = lam[1];
        float mx = fmaxf(l0, l1);
        float e0 = expf(l0 - mx), e1 = expf(l1 - mx);
        float w0 = e0 / (e0 + e1);
        out[(size_t)b*OUTC_] = w0 * sf + (1.f - w0) * scls2;
        float m2 = -1e30f;
        for (int i = 0; i < NP_ + NF_; ++i) m2 = fmaxf(m2, sc[i]);
        smax = m2;
    }
    __syncthreads();
    if (tid < NP_ + NF_) sc[tid] = expf(sc[tid] - smax);
    __syncthreads();
    if (tid == 0) {
        float s2 = 0.f;
        for (int i = 0; i < NP_ + NF_; ++i) s2 += sc[i];
        ssum = s2;
    }
    __syncthreads();
    if (tid < NP_ + NF_)
        out[(size_t)b*OUTC_ + 1 + TNF_ + tid] = sc[tid] / ssum;
}

// ---------------------------------------------------------------------------
extern "C" void kernel_launch(void* const* d_in, const int* in_sizes, int n_in,
                              void* d_out, int out_size, void* d_ws, size_t ws_size,
                              hipStream_t stream)
{
    (void)in_sizes; (void)n_in; (void)out_size; (void)ws_size;
    const float* seq  = (const float*)d_in[0];
    const float* cls  = (const float*)d_in[1];
    const int*   toff = (const int*)d_in[2];
    const int*   foff = (const int*)d_in[3];
    const float* mask = (const float*)d_in[4];
    const float* sw1  = (const float*)d_in[5];
    const float* sb1  = (const float*)d_in[6];
    const float* sw2  = (const float*)d_in[7];
    const float* sb2  = (const float*)d_in[8];
    const float* pw1  = (const float*)d_in[9];
    const float* pb1  = (const float*)d_in[10];
    const float* pw2  = (const float*)d_in[11];
    const float* pb2  = (const float*)d_in[12];
    const float* cw1  = (const float*)d_in[13];
    const float* cb1  = (const float*)d_in[14];
    const float* cw2  = (const float*)d_in[15];
    const float* cb2  = (const float*)d_in[16];
    const float* aw1  = (const float*)d_in[17];
    const float* ab1  = (const float*)d_in[18];
    const float* aw2  = (const float*)d_in[19];
    const float* ab2  = (const float*)d_in[20];
    const float* lam  = (const float*)d_in[21];

    char* wsb = (char*)d_ws;
    float*  ssent = (float*)wsb;                              // 8128 floats
    float*  sstep = ssent + NSENT_;
    float*  sabd  = sstep + NSTEP_;
    float*  scls  = sabd + NABD_;
    ushort* Abf   = (ushort*)(wsb + 65536);                   // 2.36 MB
    ushort* Wt    = Abf + (size_t)AROWS_ * H_;                // 14.68 MB
    ushort* G     = Wt + (size_t)7 * HH_;                     // 7.08 MB

    prep_kernel<<<8320, 256, 0, stream>>>(
        seq, toff, foff, cls, sw1, pw1, aw1, cw1, Abf, Wt);

    gemm_bf16_kernel<<<dim3(54, 16), 128, 0, stream>>>(Abf, Wt, G);

    combine_kernel<<<dim3(B_, 3), 256, 0, stream>>>(
        G, sb1, sw2, pb1, pw2, ab1, aw2, cb1, cw2,
        ssent, sstep, sabd, scls);

    finalize_kernel<<<B_, 128, 0, stream>>>(
        ssent, sstep, sabd, scls, mask, lam, sb2, pb2, cb2, ab2, (float*)d_out);
}

// Round 12
// 62.151 us; speedup vs baseline: 1.4448x; 1.4448x over previous
//
#include <hip/hip_runtime.h>
#include <hip/hip_bf16.h>

// Problem constants
#define B_    64
#define S_    512
#define H_    1024
#define HH_   (H_*H_)
#define T_    4
#define NF_   12
#define TNF_  48      // T*NF
#define NP_   66      // NF*(NF-1)/2
#define OUTC_ 127     // 1 + 48 + 66 + 12

// score counts
#define NSENT_ (B_*TNF_)   // 3072
#define NSTEP_ (B_*NP_)    // 4224
#define NABD_  (B_*NF_)    // 768
#define NCLS_  (B_)        // 64
#define NWAVES_ (NSENT_+NSTEP_+NABD_+NCLS_)  // 8128

// A-buffer rows (bf16, row length 1024)
#define AROW_FCT   0      // 768 rows (b*12+f)
#define AROW_TGT   768    // 256 rows (b*4+t)
#define AROW_TSD   1024   // 64 rows
#define AROW_CLS   1088   // 64 rows
#define AROWS_PAD_ 1280   // incl. pad rows for the 128-row tail tiles

// G rows (bf16, row length 1024): fsent, s1, s2, af, tsent, at, cls
#define GROW_FSENT 0
#define GROW_S1    768
#define GROW_S2    1536
#define GROW_AF    2304
#define GROW_TSENT 3072
#define GROW_AT    3328
#define GROW_CLS   3392
#define GROWS_     3456

typedef __bf16 bf16x8 __attribute__((ext_vector_type(8)));
typedef float  f32x4  __attribute__((ext_vector_type(4)));
typedef __attribute__((address_space(1))) const unsigned int gcu32;
typedef __attribute__((address_space(3))) unsigned int lu32;

__device__ __forceinline__ ushort f2bf(float x) {
    union { float f; unsigned u; } c; c.f = x;
    unsigned r = c.u + 0x7fffu + ((c.u >> 16) & 1u);
    return (ushort)(r >> 16);
}
__device__ __forceinline__ float bflo(unsigned u) {
    union { unsigned u; float f; } c; c.u = u << 16; return c.f;
}
__device__ __forceinline__ float bfhi(unsigned u) {
    union { unsigned u; float f; } c; c.u = u & 0xffff0000u; return c.f;
}

// ---------------------------------------------------------------------------
// Prep (merged): [0,1024)    segment means -> bf16 A rows (+fp32 tgt)
//                [1024,1088) cls cast
//                [1088,2880) W1 transpose-cast, 32x128 strip per block
//                            (4 independent float4 loads/thread = 4-deep MLP;
//                             fixes R11's 1-load-per-thread latency trap)
// ---------------------------------------------------------------------------
__global__ __launch_bounds__(256) void prep_kernel(
    const float* __restrict__ seq, const int* __restrict__ toffs,
    const int* __restrict__ foffs, const float* __restrict__ cls,
    const float* __restrict__ sw1, const float* __restrict__ pw1,
    const float* __restrict__ aw1, const float* __restrict__ cw1,
    float* __restrict__ tgt32, ushort* __restrict__ Abf,
    ushort* __restrict__ Wt)
{
    int blk = blockIdx.x;
    int tid = threadIdx.x;

    if (blk < 1024) {
        // ---- segment mean ----
        int b = blk >> 4;
        int k = blk & 15;
        int start, end, arow;
        float* dst32 = nullptr;
        if (k < T_) {
            start = toffs[(b*T_ + k)*2];
            end   = toffs[(b*T_ + k)*2 + 1];
            dst32 = tgt32 + (size_t)(b*T_ + k) * H_;
            arow  = AROW_TGT + b*T_ + k;
        } else {
            int f = k - T_;
            start = foffs[(b*NF_ + f)*2];
            end   = foffs[(b*NF_ + f)*2 + 1];
            arow  = AROW_FCT + b*NF_ + f;
        }
        int h0 = tid * 4;
        const float* base = seq + ((size_t)b * S_ + start) * H_ + h0;
        float4 s = make_float4(0.f, 0.f, 0.f, 0.f);
        int n = end - start;
        #pragma unroll 4
        for (int r = 0; r < n; ++r) {
            float4 v = *(const float4*)(base + (size_t)r * H_);
            s.x += v.x; s.y += v.y; s.z += v.z; s.w += v.w;
        }
        float inv = 1.f / (float)n;
        s.x *= inv; s.y *= inv; s.z *= inv; s.w *= inv;
        if (dst32) *(float4*)(dst32 + h0) = s;
        ushort4 q; q.x = f2bf(s.x); q.y = f2bf(s.y); q.z = f2bf(s.z); q.w = f2bf(s.w);
        *(ushort4*)(Abf + (size_t)arow * H_ + h0) = q;
    } else if (blk < 1088) {
        // ---- cls cast ----
        int b = blk - 1024;
        int h0 = tid * 4;
        float4 c = *(const float4*)(cls + (size_t)b * H_ + h0);
        ushort4 qc; qc.x = f2bf(c.x); qc.y = f2bf(c.y); qc.z = f2bf(c.z); qc.w = f2bf(c.w);
        *(ushort4*)(Abf + (size_t)(AROW_CLS + b) * H_ + h0) = qc;
    } else {
        // ---- transpose-cast: 32(k) x 128(n) strip of one of 7 fp32 blocks
        // src order: 0 sw1-top, 1 pw1-top, 2 pw1-bot, 3 aw1-bot, 4 sw1-bot,
        //            5 aw1-top, 6 cw1
        __shared__ float Tt[32][133];
        int idx2 = blk - 1088;          // [0, 1792)
        int z = idx2 >> 8;              // 256 strips per weight block
        int rem = idx2 & 255;
        int k0     = (rem >> 3) * 32;   // 32 k-tiles
        int nstrip = (rem & 7) * 128;   // 8 n-strips
        const float* src;
        switch (z) {
            case 0: src = sw1; break;
            case 1: src = pw1; break;
            case 2: src = pw1 + HH_; break;
            case 3: src = aw1 + HH_; break;
            case 4: src = sw1 + HH_; break;
            case 5: src = aw1; break;
            default: src = cw1; break;
        }
        int ty = tid >> 3, tx = tid & 7;
        const float* rsrc = src + (size_t)(k0 + ty) * H_ + nstrip + tx*4;
        float4 v0 = *(const float4*)(rsrc);
        float4 v1 = *(const float4*)(rsrc + 32);
        float4 v2 = *(const float4*)(rsrc + 64);
        float4 v3 = *(const float4*)(rsrc + 96);
        float4 vv[4] = {v0, v1, v2, v3};
        #pragma unroll
        for (int i = 0; i < 4; ++i) {
            Tt[ty][i*32 + tx*4 + 0] = vv[i].x;
            Tt[ty][i*32 + tx*4 + 1] = vv[i].y;
            Tt[ty][i*32 + tx*4 + 2] = vv[i].z;
            Tt[ty][i*32 + tx*4 + 3] = vv[i].w;
        }
        __syncthreads();
        #pragma unroll
        for (int i = 0; i < 4; ++i) {
            int nx = i*32 + ty;
            ushort4 q;
            q.x = f2bf(Tt[tx*4 + 0][nx]);
            q.y = f2bf(Tt[tx*4 + 1][nx]);
            q.z = f2bf(Tt[tx*4 + 2][nx]);
            q.w = f2bf(Tt[tx*4 + 3][nx]);
            *(ushort4*)(Wt + (size_t)z * HH_
                        + (size_t)(nstrip + nx) * H_ + k0 + tx*4) = q;
        }
    }
}

// tside (mean of fp32 tgt) -> bf16 row
__global__ __launch_bounds__(256) void tside_kernel(
    const float* __restrict__ tgt32, ushort* __restrict__ Abf)
{
    int b = blockIdx.x;
    int h0 = threadIdx.x * 4;
    float4 s = make_float4(0.f, 0.f, 0.f, 0.f);
    for (int t = 0; t < T_; ++t) {
        float4 v = *(const float4*)(tgt32 + (size_t)(b*T_ + t)*H_ + h0);
        s.x += v.x; s.y += v.y; s.z += v.z; s.w += v.w;
    }
    ushort4 q;
    q.x = f2bf(s.x*0.25f); q.y = f2bf(s.y*0.25f);
    q.z = f2bf(s.z*0.25f); q.w = f2bf(s.w*0.25f);
    *(ushort4*)(Abf + (size_t)(AROW_TSD + b) * H_ + h0) = q;
}

// ---------------------------------------------------------------------------
// Merged bf16 MFMA GEMM — FROZEN R6 config (best known, 62.45 total):
// 128x128 tile, BK=32, depth-2 LDS dbuf, s_waitcnt vmcnt(4) counted,
// grid (28,8). 4 waves (2x2), wave tile 64x64.
// ---------------------------------------------------------------------------
__global__ __launch_bounds__(256) void gemm_bf16_kernel(
    const ushort* __restrict__ Abf, const ushort* __restrict__ Wt,
    ushort* __restrict__ G)
{
    __shared__ __align__(16) ushort As[2][128*32];
    __shared__ __align__(16) ushort Bs[2][128*32];

    int bx = blockIdx.x;
    int arow_base, wsel, grow_base, m0, vrows;
    if (bx < 24)      { int j = bx / 6; int mt = bx % 6; arow_base = AROW_FCT;
                        wsel = j; grow_base = j * 768; m0 = mt * 128; vrows = 128; }
    else if (bx < 26) { arow_base = AROW_TGT; wsel = 4; grow_base = GROW_TSENT;
                        m0 = (bx - 24) * 128; vrows = 128; }
    else if (bx == 26){ arow_base = AROW_TSD; wsel = 5; grow_base = GROW_AT;
                        m0 = 0; vrows = 64; }
    else              { arow_base = AROW_CLS; wsel = 6; grow_base = GROW_CLS;
                        m0 = 0; vrows = 64; }

    const int tid  = threadIdx.x;
    const int lane = tid & 63;
    const int w    = tid >> 6;
    const int wr   = w >> 1, wc = w & 1;
    const int n0   = blockIdx.y * 128;

    const int srow = lane >> 2;
    const int scol = ((lane & 3) ^ ((lane >> 3) & 3)) * 8;
    const ushort* gA0 = Abf + (size_t)(arow_base + m0 + w*16 + srow) * H_ + scol;
    const ushort* gA1 = gA0 + (size_t)64 * H_;
    const ushort* gB0 = Wt + (size_t)wsel * HH_
                        + (size_t)(n0 + w*16 + srow) * H_ + scol;
    const ushort* gB1 = gB0 + (size_t)64 * H_;
    const int ldsA0 = (0*64 + w*16) * 32, ldsA1 = (1*64 + w*16) * 32;

    const int frr  = lane & 15;
    const int c0   = lane >> 4;
    const int swz  = (frr >> 1) & 3;
    const int offA = (wr*64 + frr) * 32 + (c0 ^ swz) * 8;
    const int offB = (wc*64 + frr) * 32 + (c0 ^ swz) * 8;

    f32x4 acc[4][4];
    #pragma unroll
    for (int i = 0; i < 4; ++i)
        #pragma unroll
        for (int j = 0; j < 4; ++j)
            acc[i][j] = (f32x4){0.f, 0.f, 0.f, 0.f};

    #define STAGE(buf, kstep) do {                                              \
        int kk_ = (kstep) < 32 ? (kstep) * 32 : 0;                              \
        __builtin_amdgcn_global_load_lds((gcu32*)(gA0 + kk_),                   \
            (lu32*)(As[buf] + ldsA0), 16, 0, 0);                                \
        __builtin_amdgcn_global_load_lds((gcu32*)(gA1 + kk_),                   \
            (lu32*)(As[buf] + ldsA1), 16, 0, 0);                                \
        __builtin_amdgcn_global_load_lds((gcu32*)(gB0 + kk_),                   \
            (lu32*)(Bs[buf] + ldsA0), 16, 0, 0);                                \
        __builtin_amdgcn_global_load_lds((gcu32*)(gB1 + kk_),                   \
            (lu32*)(Bs[buf] + ldsA1), 16, 0, 0);                                \
    } while (0)

    STAGE(0, 0);
    STAGE(1, 1);

    #pragma unroll 1
    for (int t = 0; t < 32; ++t) {
        const int cur = t & 1;
        asm volatile("s_waitcnt vmcnt(4)" ::: "memory");
        __builtin_amdgcn_s_barrier();
        __builtin_amdgcn_sched_barrier(0);

        const ushort* pa = As[cur] + offA;
        const ushort* pb = Bs[cur] + offB;
        bf16x8 a0 = *(const bf16x8*)(pa);
        bf16x8 a1 = *(const bf16x8*)(pa + 16*32);
        bf16x8 a2 = *(const bf16x8*)(pa + 32*32);
        bf16x8 a3 = *(const bf16x8*)(pa + 48*32);
        bf16x8 b0 = *(const bf16x8*)(pb);
        bf16x8 b1 = *(const bf16x8*)(pb + 16*32);
        bf16x8 b2 = *(const bf16x8*)(pb + 32*32);
        bf16x8 b3 = *(const bf16x8*)(pb + 48*32);

        asm volatile("s_waitcnt lgkmcnt(0)" ::: "memory");
        __builtin_amdgcn_s_barrier();
        __builtin_amdgcn_sched_barrier(0);

        if (t < 30) STAGE(cur, t + 2);

        bf16x8 av[4] = {a0, a1, a2, a3};
        bf16x8 bv[4] = {b0, b1, b2, b3};
        #pragma unroll
        for (int i = 0; i < 4; ++i)
            #pragma unroll
            for (int j = 0; j < 4; ++j)
                acc[i][j] = __builtin_amdgcn_mfma_f32_16x16x32_bf16(
                    av[i], bv[j], acc[i][j], 0, 0, 0);
    }
    #undef STAGE

    // C/D layout: col = lane&15, row = (lane>>4)*4 + reg   [verified m89]
    const int r0 = (lane >> 4) * 4;
    const int cc = lane & 15;
    #pragma unroll
    for (int i = 0; i < 4; ++i) {
        int lrow = wr*64 + i*16 + r0;
        if (lrow >= vrows) continue;
        #pragma unroll
        for (int r = 0; r < 4; ++r) {
            size_t gr = (size_t)(grow_base + m0 + lrow + r) * H_ + n0 + wc*64 + cc;
            #pragma unroll
            for (int j = 0; j < 4; ++j)
                G[gr + j*16] = f2bf(acc[i][j][r]);
        }
    }
}

// ---------------------------------------------------------------------------
// Combine: one wave per score (ungrouped — R6 known-good, 2032 blocks).
// ---------------------------------------------------------------------------
__global__ __launch_bounds__(256) void combine_kernel(
    const ushort* __restrict__ G,
    const float* __restrict__ sb1, const float* __restrict__ sw2,
    const float* __restrict__ pb1, const float* __restrict__ pw2,
    const float* __restrict__ ab1, const float* __restrict__ aw2,
    const float* __restrict__ cb1, const float* __restrict__ cw2,
    float* __restrict__ ssent, float* __restrict__ sstep,
    float* __restrict__ sabd, float* __restrict__ scls)
{
    int wv = blockIdx.x * 4 + (threadIdx.x >> 6);
    int lane = threadIdx.x & 63;
    if (wv >= NWAVES_) return;

    const ushort *U, *V;
    const float *b1, *w2;
    float* outp;
    if (wv < NSENT_) {
        int b = wv / TNF_, q = wv % TNF_;
        int t = q / NF_, f = q % NF_;
        U = G + (size_t)(GROW_FSENT + b*NF_ + f) * H_;
        V = G + (size_t)(GROW_TSENT + b*T_ + t) * H_;
        b1 = sb1; w2 = sw2; outp = ssent + wv;
    } else if (wv < NSENT_ + NSTEP_) {
        int s = wv - NSENT_;
        int b = s / NP_, p = s % NP_;
        int i = 0, rem = p, cnt = NF_ - 1;
        while (rem >= cnt) { rem -= cnt; --cnt; ++i; }
        int j = i + 1 + rem;
        U = G + (size_t)(GROW_S1 + b*NF_ + i) * H_;
        V = G + (size_t)(GROW_S2 + b*NF_ + j) * H_;
        b1 = pb1; w2 = pw2; outp = sstep + s;
    } else if (wv < NSENT_ + NSTEP_ + NABD_) {
        int s = wv - NSENT_ - NSTEP_;
        int b = s / NF_, f = s % NF_;
        U = G + (size_t)(GROW_AT + b) * H_;
        V = G + (size_t)(GROW_AF + b*NF_ + f) * H_;
        b1 = ab1; w2 = aw2; outp = sabd + s;
    } else {
        int b = wv - NSENT_ - NSTEP_ - NABD_;
        U = G + (size_t)(GROW_CLS + b) * H_;
        V = nullptr;
        b1 = cb1; w2 = cw2; outp = scls + b;
    }

    float acc = 0.f;
    #pragma unroll
    for (int h = 0; h < 2; ++h) {
        int nb = h * 512 + lane * 8;
        uint4 uu = *(const uint4*)(U + nb);
        float us[8] = { bflo(uu.x), bfhi(uu.x), bflo(uu.y), bfhi(uu.y),
                        bflo(uu.z), bfhi(uu.z), bflo(uu.w), bfhi(uu.w) };
        if (V) {
            uint4 vv = *(const uint4*)(V + nb);
            us[0] += bflo(vv.x); us[1] += bfhi(vv.x);
            us[2] += bflo(vv.y); us[3] += bfhi(vv.y);
            us[4] += bflo(vv.z); us[5] += bfhi(vv.z);
            us[6] += bflo(vv.w); us[7] += bfhi(vv.w);
        }
        float4 bA = *(const float4*)(b1 + nb);
        float4 bB = *(const float4*)(b1 + nb + 4);
        float4 wA = *(const float4*)(w2 + nb);
        float4 wB = *(const float4*)(w2 + nb + 4);
        acc = fmaf(fmaxf(us[0] + bA.x, 0.f), wA.x, acc);
        acc = fmaf(fmaxf(us[1] + bA.y, 0.f), wA.y, acc);
        acc = fmaf(fmaxf(us[2] + bA.z, 0.f), wA.z, acc);
        acc = fmaf(fmaxf(us[3] + bA.w, 0.f), wA.w, acc);
        acc = fmaf(fmaxf(us[4] + bB.x, 0.f), wB.x, acc);
        acc = fmaf(fmaxf(us[5] + bB.y, 0.f), wB.y, acc);
        acc = fmaf(fmaxf(us[6] + bB.z, 0.f), wB.z, acc);
        acc = fmaf(fmaxf(us[7] + bB.w, 0.f), wB.w, acc);
    }
    #pragma unroll
    for (int msk = 1; msk < 64; msk <<= 1)
        acc += __shfl_xor(acc, msk);
    if (lane == 0) *outp = acc;
}

// ---------------------------------------------------------------------------
// Finalize: sigmoids, masked max/mean, lambda blend, 78-way softmax, output
// ---------------------------------------------------------------------------
__global__ __launch_bounds__(128) void finalize_kernel(
    const float* __restrict__ s_sent, const float* __restrict__ s_step,
    const float* __restrict__ s_abd, const float* __restrict__ s_cls,
    const float* __restrict__ mask, const float* __restrict__ lam,
    const float* __restrict__ sent_b2, const float* __restrict__ step_b2,
    const float* __restrict__ state_b2, const float* __restrict__ abd_b2,
    float* __restrict__ out)
{
    int b = blockIdx.x;
    int tid = threadIdx.x;
    __shared__ float fs[TNF_];
    __shared__ float sc[NP_ + NF_];
    __shared__ float mpf[NF_];
    __shared__ float smax, ssum;

    if (tid < TNF_) {
        float v = 1.f / (1.f + expf(-(s_sent[b*TNF_ + tid] + sent_b2[0])));
        fs[tid] = v;
        out[(size_t)b*OUTC_ + 1 + tid] = v;
    }
    if (tid < NP_)
        sc[tid] = s_step[b*NP_ + tid] + step_b2[0];
    else if (tid < NP_ + NF_)
        sc[tid] = s_abd[b*NF_ + (tid - NP_)] + abd_b2[0];
    __syncthreads();

    if (tid < NF_) {
        float m = -1e30f;
        for (int j = 0; j < T_; ++j)
            m = fmaxf(m, fs[tid*T_ + j] * mask[((size_t)b*NF_ + tid)*T_ + j]);
        mpf[tid] = m;
    }
    __syncthreads();

    if (tid == 0) {
        float sf = 0.f;
        for (int i = 0; i < NF_; ++i) sf += mpf[i];
        sf *= (1.f / NF_);
        float scls2 = 1.f / (1.f + expf(-(s_cls[b] + state_b2[0])));
        float l0 = lam[0], l1 = lam[1];
        float mx = fmaxf(l0, l1);
        float e0 = expf(l0 - mx), e1 = expf(l1 - mx);
        float w0 = e0 / (e0 + e1);
        out[(size_t)b*OUTC_] = w0 * sf + (1.f - w0) * scls2;
        float m2 = -1e30f;
        for (int i = 0; i < NP_ + NF_; ++i) m2 = fmaxf(m2, sc[i]);
        smax = m2;
    }
    __syncthreads();
    if (tid < NP_ + NF_) sc[tid] = expf(sc[tid] - smax);
    __syncthreads();
    if (tid == 0) {
        float s2 = 0.f;
        for (int i = 0; i < NP_ + NF_; ++i) s2 += sc[i];
        ssum = s2;
    }
    __syncthreads();
    if (tid < NP_ + NF_)
        out[(size_t)b*OUTC_ + 1 + TNF_ + tid] = sc[tid] / ssum;
}

// ---------------------------------------------------------------------------
extern "C" void kernel_launch(void* const* d_in, const int* in_sizes, int n_in,
                              void* d_out, int out_size, void* d_ws, size_t ws_size,
                              hipStream_t stream)
{
    (void)in_sizes; (void)n_in; (void)out_size; (void)ws_size;
    const float* seq  = (const float*)d_in[0];
    const float* cls  = (const float*)d_in[1];
    const int*   toff = (const int*)d_in[2];
    const int*   foff = (const int*)d_in[3];
    const float* mask = (const float*)d_in[4];
    const float* sw1  = (const float*)d_in[5];
    const float* sb1  = (const float*)d_in[6];
    const float* sw2  = (const float*)d_in[7];
    const float* sb2  = (const float*)d_in[8];
    const float* pw1  = (const float*)d_in[9];
    const float* pb1  = (const float*)d_in[10];
    const float* pw2  = (const float*)d_in[11];
    const float* pb2  = (const float*)d_in[12];
    const float* cw1  = (const float*)d_in[13];
    const float* cb1  = (const float*)d_in[14];
    const float* cw2  = (const float*)d_in[15];
    const float* cb2  = (const float*)d_in[16];
    const float* aw1  = (const float*)d_in[17];
    const float* ab1  = (const float*)d_in[18];
    const float* aw2  = (const float*)d_in[19];
    const float* ab2  = (const float*)d_in[20];
    const float* lam  = (const float*)d_in[21];

    char* wsb = (char*)d_ws;
    float*  tgt32 = (float*)wsb;                              // 1 MB
    float*  ssent = (float*)(wsb + (1u<<20));                 // 8128 floats
    float*  sstep = ssent + NSENT_;
    float*  sabd  = sstep + NSTEP_;
    float*  scls  = sabd + NABD_;
    ushort* Abf   = (ushort*)(wsb + (1u<<20) + 32768);        // 1280 rows bf16
    ushort* Wt    = Abf + (size_t)AROWS_PAD_ * H_;            // 14.68 MB
    ushort* G     = Wt + (size_t)7 * HH_;                     // 7.08 MB

    prep_kernel<<<2880, 256, 0, stream>>>(
        seq, toff, foff, cls, sw1, pw1, aw1, cw1, tgt32, Abf, Wt);

    tside_kernel<<<B_, 256, 0, stream>>>(tgt32, Abf);

    gemm_bf16_kernel<<<dim3(28, 8), 256, 0, stream>>>(Abf, Wt, G);

    combine_kernel<<<(NWAVES_ + 3) / 4, 256, 0, stream>>>(
        G, sb1, sw2, pb1, pw2, ab1, aw2, cb1, cw2,
        ssent, sstep, sabd, scls);

    finalize_kernel<<<B_, 128, 0, stream>>>(
        ssent, sstep, sabd, scls, mask, lam, sb2, pb2, cb2, ab2, (float*)d_out);
}